// Round 8
// baseline (7657.961 us; speedup 1.0000x reference)
//
#include <hip/hip_runtime.h>
#include <math.h>

#define N 64
#define TRI ((N * (N + 1)) / 2)   // 2080
#define SWEEPS 20    // FIXED. 20 sweeps with the select-based rotation is the
                     // proven-correct config (R3/R4: absmax 0.015625).
                     // 8 sweeps fails (R1). Adaptive exits fail (R6).
#define WS_PER_MAT (N * N + N)    // G (row-major) + weight vector, floats

// Hand-rolled lane shuffle: 1 ds_bpermute, byte address hoisted by caller.
__device__ __forceinline__ float bperm(int byte_addr, float v) {
    return __int_as_float(
        __builtin_amdgcn_ds_bpermute(byte_addr, __float_as_int(v)));
}

// One-sided Jacobi sweeps. Thread t owns column t of G in g[].
// Column norms TRACKED (n_p' = n_p - tt*d, n_q' = n_q + tt*d), refreshed
// every sweep.
//
// ROTATION MUST BE SELECT-BASED (R5-R7 lesson): both lanes compute the
// p-frame tau = (nhi - nlo)/(2d) from role-selected nlo/nhi -- same operands
// in the same order in both lanes -> bit-identical (tau, tt, c, s) even when
// na == nb EXACTLY. Antisymmetry comes only from the `lower` selects.
// The select-FREE variant (u = (nb-na)/2d per lane) breaks on exact norm
// ties: both lanes see u = +0 with the SAME sign -> tt = +-1 in BOTH lanes
// -> the pair collapses to g_q' = -g_p' (rank loss), stalling at a wrong
// fixed point (R6/R7: bit-identical absmax 1.207 regardless of sweeps).
__device__ __forceinline__ void jacobi_sweeps(float g[N]) {
    const int t = threadIdx.x & 63;
    const int self4 = t << 2;
    for (int sw = 0; sw < SWEEPS; ++sw) {
        // refresh tracked norm (4 independent chains)
        float n0 = 0.f, n1 = 0.f, n2 = 0.f, n3 = 0.f;
        #pragma unroll
        for (int k = 0; k < N; k += 4) {
            n0 = fmaf(g[k],     g[k],     n0);
            n1 = fmaf(g[k + 1], g[k + 1], n1);
            n2 = fmaf(g[k + 2], g[k + 2], n2);
            n3 = fmaf(g[k + 3], g[k + 3], n3);
        }
        float na = (n0 + n1) + (n2 + n3);
        for (int m = 1; m < N; ++m) {
            const int pa = self4 ^ (m << 2);   // partner byte addr, once/round
            const bool lower = (self4 < pa);   // t < (t^m): role p
            float pt[N];
            float d0 = 0.f, d1 = 0.f, d2 = 0.f, d3 = 0.f;
            #pragma unroll
            for (int k = 0; k < N; k += 4) {
                pt[k]     = bperm(pa, g[k]);
                pt[k + 1] = bperm(pa, g[k + 1]);
                pt[k + 2] = bperm(pa, g[k + 2]);
                pt[k + 3] = bperm(pa, g[k + 3]);
                d0 = fmaf(g[k],     pt[k],     d0);
                d1 = fmaf(g[k + 1], pt[k + 1], d1);
                d2 = fmaf(g[k + 2], pt[k + 2], d2);
                d3 = fmaf(g[k + 3], pt[k + 3], d3);
            }
            const float d  = (d0 + d1) + (d2 + d3);   // bit-identical in pair
            const float nb = bperm(pa, na);    // partner's tracked norm
            const float nlo = lower ? na : nb; // ||g_p||^2 (p-frame, both lanes)
            const float nhi = lower ? nb : na; // ||g_q||^2
            float c = 1.f, s = 0.f, tt = 0.f;
            if (fabsf(d) > 1e-36f) {
                // inner root of t^2 + 2 tau t - 1 = 0 -> |theta| <= pi/4.
                // Tie case (nhi == nlo): tau = +-0 -> tt = +-1, a coherent
                // 45-degree rotation (legitimate; zeroes the coupling).
                const float tau = (nhi - nlo) / (2.f * d);
                tt = copysignf(
                    1.f / (fabsf(tau) + sqrtf(fmaf(tau, tau, 1.f))), tau);
                c = rsqrtf(fmaf(tt, tt, 1.f));
                s = tt * c;
            }
            const float se = lower ? -s : s;   // p: c*own - s*part ; q: +s
            const float st = lower ? -tt : tt;
            na = fmaf(st, d, na);              // analytic norm update
            #pragma unroll
            for (int k = 0; k < N; ++k) g[k] = fmaf(se, pt[k], c * g[k]);
        }
    }
}

// Phase 1: sweeps only, zero LDS. Plain launch_bounds(64): the (64,3)
// variant (R4) caused scratch spills (+30 MB HBM traffic).
__global__ __launch_bounds__(64)
void jacobi_kernel(const float* __restrict__ X, float* __restrict__ ws) {
    const int b = blockIdx.x;
    const int t = threadIdx.x;
    const float* __restrict__ Xb = X + (size_t)b * (N * N);
    float g[N];
    #pragma unroll
    for (int k = 0; k < N; ++k) g[k] = Xb[k * N + t];   // coalesced rows
    jacobi_sweeps(g);
    float* __restrict__ wb = ws + (size_t)b * WS_PER_MAT;
    float nown = 0.f;
    #pragma unroll
    for (int k = 0; k < N; ++k) {
        wb[k * N + t] = g[k];
        nown = fmaf(g[k], g[k], nown);
    }
    float sv = sqrtf(nown);
    sv = fminf(fmaxf(sv, 1e-4f), 1e4f);
    wb[N * N + t] = logf(sv) / fmaxf(nown, 1e-12f);     // w_k = log s / s^2
}

// Phase 2: logm[i][j] = sum_t w_t S[i][t] S[j][t], 4x4 register tile per
// thread, triu-only coalesced writes.
__global__ __launch_bounds__(256)
void outer_kernel(const float* __restrict__ ws, float* __restrict__ out) {
    __shared__ float S[N][N + 1];
    __shared__ float wv[N];
    const int b = blockIdx.x;
    const int tid = threadIdx.x;
    const float* __restrict__ wb = ws + (size_t)b * WS_PER_MAT;
    for (int idx = tid; idx < N * N; idx += 256)
        S[idx >> 6][idx & 63] = wb[idx];
    if (tid < N) wv[tid] = wb[N * N + tid];
    __syncthreads();
    const int tx = tid & 15, ty = tid >> 4;
    const int i0 = ty * 4, j0 = tx * 4;
    float acc[4][4];
    #pragma unroll
    for (int r = 0; r < 4; ++r)
        #pragma unroll
        for (int c_ = 0; c_ < 4; ++c_) acc[r][c_] = 0.f;
    #pragma unroll 8
    for (int t = 0; t < N; ++t) {
        const float w = wv[t];
        float si[4], sj[4];
        #pragma unroll
        for (int r = 0; r < 4; ++r) si[r] = w * S[i0 + r][t];
        #pragma unroll
        for (int c_ = 0; c_ < 4; ++c_) sj[c_] = S[j0 + c_][t];
        #pragma unroll
        for (int r = 0; r < 4; ++r)
            #pragma unroll
            for (int c_ = 0; c_ < 4; ++c_)
                acc[r][c_] = fmaf(si[r], sj[c_], acc[r][c_]);
    }
    float* __restrict__ ob = out + (size_t)b * TRI;
    #pragma unroll
    for (int r = 0; r < 4; ++r) {
        const int i = i0 + r;
        const int st = i * (2 * N + 1 - i) / 2;
        #pragma unroll
        for (int c_ = 0; c_ < 4; ++c_) {
            const int j = j0 + c_;
            if (j >= i) ob[st + (j - i)] = acc[r][c_];
        }
    }
}

// Fallback if ws_size too small: fused sweeps + LDS epilogue.
__global__ __launch_bounds__(64)
void fused_kernel(const float* __restrict__ X, float* __restrict__ out) {
    __shared__ float Gt[N][N + 1];
    __shared__ float w[N];
    const int b = blockIdx.x;
    const int t = threadIdx.x;
    const float* __restrict__ Xb = X + (size_t)b * (N * N);
    float g[N];
    #pragma unroll
    for (int k = 0; k < N; ++k) g[k] = Xb[k * N + t];
    jacobi_sweeps(g);
    float nown = 0.f;
    #pragma unroll
    for (int k = 0; k < N; ++k) {
        Gt[t][k] = g[k];
        nown = fmaf(g[k], g[k], nown);
    }
    float sv = sqrtf(nown);
    sv = fminf(fmaxf(sv, 1e-4f), 1e4f);
    w[t] = logf(sv) / fmaxf(nown, 1e-12f);
    __syncthreads();
    float wr[N];
    #pragma unroll
    for (int k = 0; k < N; ++k) wr[k] = w[k];
    float* __restrict__ ob = out + (size_t)b * TRI;
    int i = 0, base = 0;
    for (int e = t; e < TRI; e += N) {
        while (base + (N - i) <= e) { base += (N - i); ++i; }
        const int j = i + (e - base);
        float acc = 0.f;
        #pragma unroll
        for (int k = 0; k < N; ++k)
            acc = fmaf(wr[k] * Gt[k][i], Gt[k][j], acc);
        ob[e] = acc;
    }
}

extern "C" void kernel_launch(void* const* d_in, const int* in_sizes, int n_in,
                              void* d_out, int out_size, void* d_ws, size_t ws_size,
                              hipStream_t stream) {
    const float* x = (const float*)d_in[0];
    float* out = (float*)d_out;
    const int B = in_sizes[0] / (N * N);   // 8192
    const size_t need = (size_t)B * WS_PER_MAT * sizeof(float);  // ~136 MB
    if (ws_size >= need) {
        jacobi_kernel<<<dim3(B), dim3(64), 0, stream>>>(x, (float*)d_ws);
        outer_kernel<<<dim3(B), dim3(256), 0, stream>>>((const float*)d_ws, out);
    } else {
        fused_kernel<<<dim3(B), dim3(64), 0, stream>>>(x, out);
    }
}

// Round 9
// 6803.991 us; speedup vs baseline: 1.1255x; 1.1255x over previous
//
#include <hip/hip_runtime.h>
#include <math.h>

#define N 64
#define TRI ((N * (N + 1)) / 2)   // 2080
#define MAX_SWEEPS 20
#define TOL2 1e-10f  // R3-PROVEN: with select-based rotation, exit at 1e-10
                     // fires (~11 avg sweeps, 4.8ms vs 8.8ms for fixed-20 in
                     // R8) AND passes at absmax 0.015625 (the floor).
#define WPB 4        // matrices (waves) per block: 1-wave blocks hit the
                     // per-CU workgroup-slot cap (Occupancy 22.5% at VGPR=88,
                     // which allows 5 waves/SIMD); 4-wave blocks lift it.
#define WS_PER_MAT (N * N + N)    // G (row-major) + weight vector, floats

// Hand-rolled lane shuffle: 1 ds_bpermute, byte address hoisted by caller.
// Wave-level op: addr selects source lane (byte addr = lane<<2) within the
// wave -- valid in multi-wave blocks.
__device__ __forceinline__ float bperm(int byte_addr, float v) {
    return __int_as_float(
        __builtin_amdgcn_ds_bpermute(byte_addr, __float_as_int(v)));
}

// One-sided Jacobi sweeps. Lane t of its wave owns column t of G.
// Column norms TRACKED (n_p' = n_p - tt*d, n_q' = n_q + tt*d), refreshed
// every sweep.
//
// ROTATION MUST BE SELECT-BASED (R5-R7 lesson): both lanes compute the
// p-frame tau = (nhi - nlo)/(2d) from role-selected nlo/nhi -- same operands
// in the same order in both lanes -> bit-identical (tau, tt, c, s) even when
// na == nb EXACTLY. Antisymmetry comes only from the `lower` selects.
// The select-FREE variant (u = (nb-na)/2d per lane) breaks on exact norm
// ties: both lanes see u = +0 with the SAME sign -> tt = +-1 in BOTH lanes
// -> the pair collapses to g_q' = -g_p' (rank loss), stalling at a wrong
// fixed point (R6/R7: bit-identical absmax 1.207 regardless of sweeps).
//
// EARLY EXIT at TOL2=1e-10 is per-wave (__any = 64-bit wave ballot), so
// waves in a multi-wave block exit independently -- no block sync needed.
__device__ __forceinline__ void jacobi_sweeps(float g[N]) {
    const int t = threadIdx.x & 63;
    const int self4 = t << 2;
    for (int sw = 0; sw < MAX_SWEEPS; ++sw) {
        // refresh tracked norm (4 independent chains)
        float n0 = 0.f, n1 = 0.f, n2 = 0.f, n3 = 0.f;
        #pragma unroll
        for (int k = 0; k < N; k += 4) {
            n0 = fmaf(g[k],     g[k],     n0);
            n1 = fmaf(g[k + 1], g[k + 1], n1);
            n2 = fmaf(g[k + 2], g[k + 2], n2);
            n3 = fmaf(g[k + 3], g[k + 3], n3);
        }
        float na = (n0 + n1) + (n2 + n3);
        int bad = 0;
        for (int m = 1; m < N; ++m) {
            const int pa = self4 ^ (m << 2);   // partner byte addr, once/round
            const bool lower = (self4 < pa);   // t < (t^m): role p
            float pt[N];
            float d0 = 0.f, d1 = 0.f, d2 = 0.f, d3 = 0.f;
            #pragma unroll
            for (int k = 0; k < N; k += 4) {
                pt[k]     = bperm(pa, g[k]);
                pt[k + 1] = bperm(pa, g[k + 1]);
                pt[k + 2] = bperm(pa, g[k + 2]);
                pt[k + 3] = bperm(pa, g[k + 3]);
                d0 = fmaf(g[k],     pt[k],     d0);
                d1 = fmaf(g[k + 1], pt[k + 1], d1);
                d2 = fmaf(g[k + 2], pt[k + 2], d2);
                d3 = fmaf(g[k + 3], pt[k + 3], d3);
            }
            const float d  = (d0 + d1) + (d2 + d3);   // bit-identical in pair
            const float nb = bperm(pa, na);    // partner's tracked norm
            bad |= (d * d > TOL2 * na * nb);   // fresh, pre-rotation measure
            const float nlo = lower ? na : nb; // ||g_p||^2 (p-frame)
            const float nhi = lower ? nb : na; // ||g_q||^2
            float c = 1.f, s = 0.f, tt = 0.f;
            if (fabsf(d) > 1e-36f) {
                // inner root of t^2 + 2 tau t - 1 = 0 -> |theta| <= pi/4.
                const float tau = (nhi - nlo) / (2.f * d);
                tt = copysignf(
                    1.f / (fabsf(tau) + sqrtf(fmaf(tau, tau, 1.f))), tau);
                c = rsqrtf(fmaf(tt, tt, 1.f));
                s = tt * c;
            }
            const float se = lower ? -s : s;   // p: c*own - s*part ; q: +s
            const float st = lower ? -tt : tt;
            na = fmaf(st, d, na);              // analytic norm update
            #pragma unroll
            for (int k = 0; k < N; ++k) g[k] = fmaf(se, pt[k], c * g[k]);
        }
        if (!__any(bad)) break;                // per-wave exit (R3-proven)
    }
}

// Phase 1: sweeps only, zero LDS, WPB matrices per 256-thread block.
// Plain launch_bounds (the (64,3) variant in R4 caused scratch spills).
__global__ __launch_bounds__(64 * WPB)
void jacobi_kernel(const float* __restrict__ X, float* __restrict__ ws,
                   int B) {
    const int b = blockIdx.x * WPB + (threadIdx.x >> 6);
    if (b >= B) return;
    const int t = threadIdx.x & 63;
    const float* __restrict__ Xb = X + (size_t)b * (N * N);
    float g[N];
    #pragma unroll
    for (int k = 0; k < N; ++k) g[k] = Xb[k * N + t];   // coalesced rows
    jacobi_sweeps(g);
    float* __restrict__ wb = ws + (size_t)b * WS_PER_MAT;
    float nown = 0.f;
    #pragma unroll
    for (int k = 0; k < N; ++k) {
        wb[k * N + t] = g[k];
        nown = fmaf(g[k], g[k], nown);
    }
    float sv = sqrtf(nown);
    sv = fminf(fmaxf(sv, 1e-4f), 1e4f);
    wb[N * N + t] = logf(sv) / fmaxf(nown, 1e-12f);     // w_k = log s / s^2
}

// Phase 2: logm[i][j] = sum_t w_t S[i][t] S[j][t], 4x4 register tile per
// thread, triu-only coalesced writes.
__global__ __launch_bounds__(256)
void outer_kernel(const float* __restrict__ ws, float* __restrict__ out) {
    __shared__ float S[N][N + 1];
    __shared__ float wv[N];
    const int b = blockIdx.x;
    const int tid = threadIdx.x;
    const float* __restrict__ wb = ws + (size_t)b * WS_PER_MAT;
    for (int idx = tid; idx < N * N; idx += 256)
        S[idx >> 6][idx & 63] = wb[idx];
    if (tid < N) wv[tid] = wb[N * N + tid];
    __syncthreads();
    const int tx = tid & 15, ty = tid >> 4;
    const int i0 = ty * 4, j0 = tx * 4;
    float acc[4][4];
    #pragma unroll
    for (int r = 0; r < 4; ++r)
        #pragma unroll
        for (int c_ = 0; c_ < 4; ++c_) acc[r][c_] = 0.f;
    #pragma unroll 8
    for (int t = 0; t < N; ++t) {
        const float w = wv[t];
        float si[4], sj[4];
        #pragma unroll
        for (int r = 0; r < 4; ++r) si[r] = w * S[i0 + r][t];
        #pragma unroll
        for (int c_ = 0; c_ < 4; ++c_) sj[c_] = S[j0 + c_][t];
        #pragma unroll
        for (int r = 0; r < 4; ++r)
            #pragma unroll
            for (int c_ = 0; c_ < 4; ++c_)
                acc[r][c_] = fmaf(si[r], sj[c_], acc[r][c_]);
    }
    float* __restrict__ ob = out + (size_t)b * TRI;
    #pragma unroll
    for (int r = 0; r < 4; ++r) {
        const int i = i0 + r;
        const int st = i * (2 * N + 1 - i) / 2;
        #pragma unroll
        for (int c_ = 0; c_ < 4; ++c_) {
            const int j = j0 + c_;
            if (j >= i) ob[st + (j - i)] = acc[r][c_];
        }
    }
}

// Fallback if ws_size too small: fused sweeps + LDS epilogue (1 wave/block).
__global__ __launch_bounds__(64)
void fused_kernel(const float* __restrict__ X, float* __restrict__ out) {
    __shared__ float Gt[N][N + 1];
    __shared__ float w[N];
    const int b = blockIdx.x;
    const int t = threadIdx.x;
    const float* __restrict__ Xb = X + (size_t)b * (N * N);
    float g[N];
    #pragma unroll
    for (int k = 0; k < N; ++k) g[k] = Xb[k * N + t];
    jacobi_sweeps(g);
    float nown = 0.f;
    #pragma unroll
    for (int k = 0; k < N; ++k) {
        Gt[t][k] = g[k];
        nown = fmaf(g[k], g[k], nown);
    }
    float sv = sqrtf(nown);
    sv = fminf(fmaxf(sv, 1e-4f), 1e4f);
    w[t] = logf(sv) / fmaxf(nown, 1e-12f);
    __syncthreads();
    float wr[N];
    #pragma unroll
    for (int k = 0; k < N; ++k) wr[k] = w[k];
    float* __restrict__ ob = out + (size_t)b * TRI;
    int i = 0, base = 0;
    for (int e = t; e < TRI; e += N) {
        while (base + (N - i) <= e) { base += (N - i); ++i; }
        const int j = i + (e - base);
        float acc = 0.f;
        #pragma unroll
        for (int k = 0; k < N; ++k)
            acc = fmaf(wr[k] * Gt[k][i], Gt[k][j], acc);
        ob[e] = acc;
    }
}

extern "C" void kernel_launch(void* const* d_in, const int* in_sizes, int n_in,
                              void* d_out, int out_size, void* d_ws, size_t ws_size,
                              hipStream_t stream) {
    const float* x = (const float*)d_in[0];
    float* out = (float*)d_out;
    const int B = in_sizes[0] / (N * N);   // 8192
    const size_t need = (size_t)B * WS_PER_MAT * sizeof(float);  // ~136 MB
    if (ws_size >= need) {
        const int nblk = (B + WPB - 1) / WPB;
        jacobi_kernel<<<dim3(nblk), dim3(64 * WPB), 0, stream>>>(
            x, (float*)d_ws, B);
        outer_kernel<<<dim3(B), dim3(256), 0, stream>>>((const float*)d_ws, out);
    } else {
        fused_kernel<<<dim3(B), dim3(64), 0, stream>>>(x, out);
    }
}

// Round 10
// 4746.973 us; speedup vs baseline: 1.6132x; 1.4333x over previous
//
#include <hip/hip_runtime.h>
#include <math.h>

#define N 64
#define HALF 32
#define TRI ((N * (N + 1)) / 2)   // 2080
#define MAX_SWEEPS 20
#define TOL2 1e-10f  // PROVEN (R3, R9): exit fires (~11 avg sweeps) AND
                     // passes at the 0.015625 floor with select-based rotation.
#define WS_PER_MAT (N * N + N)    // G (row-major) + weight vector, floats

// Hand-rolled lane shuffle: 1 ds_bpermute, byte address hoisted by caller.
// Wave-scoped (addr = lane-in-wave << 2): valid per-wave in multi-wave blocks.
__device__ __forceinline__ float bperm(int byte_addr, float v) {
    return __int_as_float(
        __builtin_amdgcn_ds_bpermute(byte_addr, __float_as_int(v)));
}

// ---------------------------------------------------------------------------
// Phase 1: one MATRIX per 128-thread block, rows split across the 2 waves.
// Lane t of wave w owns column t rows [32w,32w+32) in g[32] (halves VGPR and
// per-step latency vs the 1-wave version; R3/R8/R9 showed pure latency bound:
// throughput ~ resident waves x per-wave ILP).
//
// Cross-wave combine: per step each lane contributes one partial dot; summed
// in WAVE-INDEX order (d = p0 + p1) -> bit-identical d in all 4 lanes of a
// pair -> coherent rotations in both waves AND identical per-wave __any(bad)
// -> waves always exit the same sweep (no divergent barriers).
//
// ROTATION MUST BE SELECT-BASED (R5-R7 lesson): both lanes compute the
// p-frame tau from role-selected nlo/nhi (same operands, same order ->
// bit-identical even on exact norm ties). The select-free variant collapses
// tied pairs to rank-1 (R6/R7: stalled at absmax 1.207).
//
// Barrier safety (1 barrier/step): step m writes slot (m&1), SYNC, reads.
// Next write to that slot is step m+2, after SYNC@(m+1), which the reader
// only passes after completing step m's read -> no WAR race. Refresh and
// epilogue use slot 2 with write->SYNC->read and are separated from their
// next reuse by the 63 step-barriers of the sweep.
// ---------------------------------------------------------------------------
__global__ __launch_bounds__(128)
void jacobi2_kernel(const float* __restrict__ X, float* __restrict__ ws) {
    __shared__ float xbuf[3][2][64];   // [slot][wave][lane]
    const int b   = blockIdx.x;
    const int tid = threadIdx.x;
    const int t   = tid & 63;
    const int wid = tid >> 6;          // 0: rows 0-31, 1: rows 32-63
    const int self4 = t << 2;
    const float* __restrict__ Xb = X + (size_t)b * (N * N);

    float g[HALF];
    #pragma unroll
    for (int k = 0; k < HALF; ++k)
        g[k] = Xb[(wid * HALF + k) * N + t];   // coalesced 256B rows

    float na = 0.f;
    for (int sw = 0; sw < MAX_SWEEPS; ++sw) {
        // --- refresh full column norm: partial + ordered cross-wave sum
        float n0 = 0.f, n1 = 0.f, n2 = 0.f, n3 = 0.f;
        #pragma unroll
        for (int k = 0; k < HALF; k += 4) {
            n0 = fmaf(g[k],     g[k],     n0);
            n1 = fmaf(g[k + 1], g[k + 1], n1);
            n2 = fmaf(g[k + 2], g[k + 2], n2);
            n3 = fmaf(g[k + 3], g[k + 3], n3);
        }
        const float pn = (n0 + n1) + (n2 + n3);
        xbuf[2][wid][t] = pn;
        __syncthreads();
        {
            const float on = xbuf[2][wid ^ 1][t];
            const float lo = (wid == 0) ? pn : on;   // wave0 partial first
            const float hi = (wid == 0) ? on : pn;
            na = lo + hi;                            // identical in both waves
        }
        int bad = 0;
        for (int m = 1; m < N; ++m) {
            const int pa = self4 ^ (m << 2);   // partner byte addr
            const bool lower = (self4 < pa);   // column role p
            float pt[HALF];
            float d0 = 0.f, d1 = 0.f, d2 = 0.f, d3 = 0.f;
            #pragma unroll
            for (int k = 0; k < HALF; k += 4) {
                pt[k]     = bperm(pa, g[k]);
                pt[k + 1] = bperm(pa, g[k + 1]);
                pt[k + 2] = bperm(pa, g[k + 2]);
                pt[k + 3] = bperm(pa, g[k + 3]);
                d0 = fmaf(g[k],     pt[k],     d0);
                d1 = fmaf(g[k + 1], pt[k + 1], d1);
                d2 = fmaf(g[k + 2], pt[k + 2], d2);
                d3 = fmaf(g[k + 3], pt[k + 3], d3);
            }
            const float pd = (d0 + d1) + (d2 + d3);
            const int slot = m & 1;
            xbuf[slot][wid][t] = pd;
            __syncthreads();
            const float od  = xbuf[slot][wid ^ 1][t];
            const float dlo = (wid == 0) ? pd : od;
            const float dhi = (wid == 0) ? od : pd;
            const float d   = dlo + dhi;        // bit-identical everywhere
            const float nb  = bperm(pa, na);    // partner's full norm
            bad |= (d * d > TOL2 * na * nb);
            const float nlo = lower ? na : nb;  // p-frame (both lanes/waves)
            const float nhi = lower ? nb : na;
            float c = 1.f, s = 0.f, tt = 0.f;
            if (fabsf(d) > 1e-36f) {
                // inner root of t^2 + 2 tau t - 1 = 0 -> |theta| <= pi/4
                const float tau = (nhi - nlo) / (2.f * d);
                tt = copysignf(
                    1.f / (fabsf(tau) + sqrtf(fmaf(tau, tau, 1.f))), tau);
                c = rsqrtf(fmaf(tt, tt, 1.f));
                s = tt * c;
            }
            const float se = lower ? -s : s;    // p: c*own - s*part ; q: +s
            const float st = lower ? -tt : tt;
            na = fmaf(st, d, na);               // analytic full-norm update
            #pragma unroll
            for (int k = 0; k < HALF; ++k) g[k] = fmaf(se, pt[k], c * g[k]);
        }
        if (!__any(bad)) break;   // identical in both waves -> joint exit
    }

    // Final exact norm (fresh, exchanged) + stage G and weights.
    float n0 = 0.f, n1 = 0.f, n2 = 0.f, n3 = 0.f;
    #pragma unroll
    for (int k = 0; k < HALF; k += 4) {
        n0 = fmaf(g[k],     g[k],     n0);
        n1 = fmaf(g[k + 1], g[k + 1], n1);
        n2 = fmaf(g[k + 2], g[k + 2], n2);
        n3 = fmaf(g[k + 3], g[k + 3], n3);
    }
    const float pn = (n0 + n1) + (n2 + n3);
    xbuf[2][wid][t] = pn;
    __syncthreads();
    const float on = xbuf[2][wid ^ 1][t];
    const float nown = ((wid == 0) ? pn : on) + ((wid == 0) ? on : pn);

    float* __restrict__ wb = ws + (size_t)b * WS_PER_MAT;
    #pragma unroll
    for (int k = 0; k < HALF; ++k)
        wb[(wid * HALF + k) * N + t] = g[k];    // coalesced
    if (wid == 0) {
        float sv = sqrtf(nown);
        sv = fminf(fmaxf(sv, 1e-4f), 1e4f);
        wb[N * N + t] = logf(sv) / fmaxf(nown, 1e-12f);  // w = log s / s^2
    }
}

// ---------------------------------------------------------------------------
// Phase 2: logm[i][j] = sum_t w_t S[i][t] S[j][t], 4x4 register tile per
// thread, triu-only coalesced writes. (small vs phase 1)
// ---------------------------------------------------------------------------
__global__ __launch_bounds__(256)
void outer_kernel(const float* __restrict__ ws, float* __restrict__ out) {
    __shared__ float S[N][N + 1];
    __shared__ float wv[N];
    const int b = blockIdx.x;
    const int tid = threadIdx.x;
    const float* __restrict__ wb = ws + (size_t)b * WS_PER_MAT;
    for (int idx = tid; idx < N * N; idx += 256)
        S[idx >> 6][idx & 63] = wb[idx];
    if (tid < N) wv[tid] = wb[N * N + tid];
    __syncthreads();
    const int tx = tid & 15, ty = tid >> 4;
    const int i0 = ty * 4, j0 = tx * 4;
    float acc[4][4];
    #pragma unroll
    for (int r = 0; r < 4; ++r)
        #pragma unroll
        for (int c_ = 0; c_ < 4; ++c_) acc[r][c_] = 0.f;
    #pragma unroll 8
    for (int t = 0; t < N; ++t) {
        const float w = wv[t];
        float si[4], sj[4];
        #pragma unroll
        for (int r = 0; r < 4; ++r) si[r] = w * S[i0 + r][t];
        #pragma unroll
        for (int c_ = 0; c_ < 4; ++c_) sj[c_] = S[j0 + c_][t];
        #pragma unroll
        for (int r = 0; r < 4; ++r)
            #pragma unroll
            for (int c_ = 0; c_ < 4; ++c_)
                acc[r][c_] = fmaf(si[r], sj[c_], acc[r][c_]);
    }
    float* __restrict__ ob = out + (size_t)b * TRI;
    #pragma unroll
    for (int r = 0; r < 4; ++r) {
        const int i = i0 + r;
        const int st = i * (2 * N + 1 - i) / 2;
        #pragma unroll
        for (int c_ = 0; c_ < 4; ++c_) {
            const int j = j0 + c_;
            if (j >= i) ob[st + (j - i)] = acc[r][c_];
        }
    }
}

// ---------------------------------------------------------------------------
// Fallback (ws too small): 1-wave-per-matrix fused kernel, R8/R9-proven math.
// ---------------------------------------------------------------------------
__device__ __forceinline__ void jacobi_sweeps1(float g[N]) {
    const int t = threadIdx.x & 63;
    const int self4 = t << 2;
    for (int sw = 0; sw < MAX_SWEEPS; ++sw) {
        float n0 = 0.f, n1 = 0.f, n2 = 0.f, n3 = 0.f;
        #pragma unroll
        for (int k = 0; k < N; k += 4) {
            n0 = fmaf(g[k],     g[k],     n0);
            n1 = fmaf(g[k + 1], g[k + 1], n1);
            n2 = fmaf(g[k + 2], g[k + 2], n2);
            n3 = fmaf(g[k + 3], g[k + 3], n3);
        }
        float na = (n0 + n1) + (n2 + n3);
        int bad = 0;
        for (int m = 1; m < N; ++m) {
            const int pa = self4 ^ (m << 2);
            const bool lower = (self4 < pa);
            float pt[N];
            float d0 = 0.f, d1 = 0.f, d2 = 0.f, d3 = 0.f;
            #pragma unroll
            for (int k = 0; k < N; k += 4) {
                pt[k]     = bperm(pa, g[k]);
                pt[k + 1] = bperm(pa, g[k + 1]);
                pt[k + 2] = bperm(pa, g[k + 2]);
                pt[k + 3] = bperm(pa, g[k + 3]);
                d0 = fmaf(g[k],     pt[k],     d0);
                d1 = fmaf(g[k + 1], pt[k + 1], d1);
                d2 = fmaf(g[k + 2], pt[k + 2], d2);
                d3 = fmaf(g[k + 3], pt[k + 3], d3);
            }
            const float d  = (d0 + d1) + (d2 + d3);
            const float nb = bperm(pa, na);
            bad |= (d * d > TOL2 * na * nb);
            const float nlo = lower ? na : nb;
            const float nhi = lower ? nb : na;
            float c = 1.f, s = 0.f, tt = 0.f;
            if (fabsf(d) > 1e-36f) {
                const float tau = (nhi - nlo) / (2.f * d);
                tt = copysignf(
                    1.f / (fabsf(tau) + sqrtf(fmaf(tau, tau, 1.f))), tau);
                c = rsqrtf(fmaf(tt, tt, 1.f));
                s = tt * c;
            }
            const float se = lower ? -s : s;
            const float st = lower ? -tt : tt;
            na = fmaf(st, d, na);
            #pragma unroll
            for (int k = 0; k < N; ++k) g[k] = fmaf(se, pt[k], c * g[k]);
        }
        if (!__any(bad)) break;
    }
}

__global__ __launch_bounds__(64)
void fused_kernel(const float* __restrict__ X, float* __restrict__ out) {
    __shared__ float Gt[N][N + 1];
    __shared__ float w[N];
    const int b = blockIdx.x;
    const int t = threadIdx.x;
    const float* __restrict__ Xb = X + (size_t)b * (N * N);
    float g[N];
    #pragma unroll
    for (int k = 0; k < N; ++k) g[k] = Xb[k * N + t];
    jacobi_sweeps1(g);
    float nown = 0.f;
    #pragma unroll
    for (int k = 0; k < N; ++k) {
        Gt[t][k] = g[k];
        nown = fmaf(g[k], g[k], nown);
    }
    float sv = sqrtf(nown);
    sv = fminf(fmaxf(sv, 1e-4f), 1e4f);
    w[t] = logf(sv) / fmaxf(nown, 1e-12f);
    __syncthreads();
    float wr[N];
    #pragma unroll
    for (int k = 0; k < N; ++k) wr[k] = w[k];
    float* __restrict__ ob = out + (size_t)b * TRI;
    int i = 0, base = 0;
    for (int e = t; e < TRI; e += N) {
        while (base + (N - i) <= e) { base += (N - i); ++i; }
        const int j = i + (e - base);
        float acc = 0.f;
        #pragma unroll
        for (int k = 0; k < N; ++k)
            acc = fmaf(wr[k] * Gt[k][i], Gt[k][j], acc);
        ob[e] = acc;
    }
}

extern "C" void kernel_launch(void* const* d_in, const int* in_sizes, int n_in,
                              void* d_out, int out_size, void* d_ws, size_t ws_size,
                              hipStream_t stream) {
    const float* x = (const float*)d_in[0];
    float* out = (float*)d_out;
    const int B = in_sizes[0] / (N * N);   // 8192
    const size_t need = (size_t)B * WS_PER_MAT * sizeof(float);  // ~136 MB
    if (ws_size >= need) {
        jacobi2_kernel<<<dim3(B), dim3(128), 0, stream>>>(x, (float*)d_ws);
        outer_kernel<<<dim3(B), dim3(256), 0, stream>>>((const float*)d_ws, out);
    } else {
        fused_kernel<<<dim3(B), dim3(64), 0, stream>>>(x, out);
    }
}